// Round 3
// baseline (576823.389 us; speedup 1.0000x reference)
//
#include <hip/hip_runtime.h>
#include <hip/hip_bf16.h>

// TrainerRNN: 10-layer GRU (T=2048, IN=384, H=768) + linear head (384).
// ROUND 2: barrier rework. R1 passed (absmax 4.9e-4) at 499 ms = 24.4 us/step,
// entirely barrier-bound (VALUBusy 0.97%): 256 atomic RMWs to ONE LLC line,
// serialized against 256 spinning pollers. Fix:
//  - Arrive = plain device-scope store to per-block padded slot (no RMW).
//  - Dedicated checker block (grid=257) scans slots with one wave, then
//    stores a single release flag; compute blocks poll only the flag.
//  - gi (input-projection) for step t+1 prefetched between arrive and wait
//    (independent of h_t) -> hidden inside barrier latency.
// Fencing pattern preserved from R1 (which passed cross-XCD): threadfence
// before arrive, RELEASE arrive/flag stores, ACQUIRE flag poll, syncthreads.

#define T_SEQ 2048
#define H_DIM 768
#define IN0   384
#define G3    2304      // 3*H
#define NLAYER 10
#define NBLK  256       // compute blocks; block NBLK is the checker
#define NTHR  192       // 3 waves, one per owned hidden unit
#define NOUT  384
#define SLOT_STRIDE 32  // 128 B per slot, in uint32 units

__device__ __forceinline__ float sigm(float x) { return 1.0f / (1.0f + __expf(-x)); }

extern "C" __global__ __launch_bounds__(NTHR, 1) void gru_persistent(
    const float* __restrict__ x,
    const float* __restrict__ wih0,
    const float* __restrict__ whh0,
    const float* __restrict__ bih0,
    const float* __restrict__ bhh0,
    const float* __restrict__ wihS,
    const float* __restrict__ whhS,
    const float* __restrict__ bihS,
    const float* __restrict__ bhhS,
    float* __restrict__ buf0, float* __restrict__ buf1,
    unsigned int* __restrict__ ctr)
{
    __shared__ float lds[3 * 6 * H_DIM];   // 3 units * 4608 floats = 54 KB

    const int tid  = threadIdx.x;
    const int bid  = blockIdx.x;
    unsigned int* const flag  = ctr;            // release flag (line 0)
    unsigned int* const slots = ctr + 256;      // 256 slots, 128 B apart

    // ---------------- dedicated checker block ----------------
    if (bid == NBLK) {
        if (tid < 64) {
            const unsigned int total = (unsigned int)NLAYER * T_SEQ;
            for (unsigned int s = 1; s <= total; ++s) {
                for (;;) {
                    int ok = 1;
#pragma unroll
                    for (int k = 0; k < 4; ++k) {
                        unsigned int v = __hip_atomic_load(
                            &slots[(tid + 64 * k) * SLOT_STRIDE],
                            __ATOMIC_RELAXED, __HIP_MEMORY_SCOPE_AGENT);
                        ok &= (v >= s) ? 1 : 0;
                    }
                    if (__all(ok)) break;
                    __builtin_amdgcn_s_sleep(1);
                }
                __threadfence();
                if (tid == 0)
                    __hip_atomic_store(flag, s, __ATOMIC_RELEASE,
                                       __HIP_MEMORY_SCOPE_AGENT);
            }
        }
        return;
    }

    // ---------------- compute blocks ----------------
    const int lane = tid & 63;
    const int wv   = tid >> 6;             // 0..2
    const int j    = bid * 3 + wv;         // owned hidden unit, 0..767
    unsigned int gstep = 0;

    for (int l = 0; l < NLAYER; ++l) {
        const int Din = (l == 0) ? IN0 : H_DIM;
        const float* wih = (l == 0) ? wih0 : wihS + (size_t)(l - 1) * G3 * H_DIM;
        const float* whh = (l == 0) ? whh0 : whhS + (size_t)(l - 1) * G3 * H_DIM;
        const float* bih = (l == 0) ? bih0 : bihS + (size_t)(l - 1) * G3;
        const float* bhh = (l == 0) ? bhh0 : bhhS + (size_t)(l - 1) * G3;
        const float* yp = (l & 1) ? buf0 : buf1;   // prev layer output (l>0)
        float*       yc = (l & 1) ? buf1 : buf0;   // this layer's output

        // ---- stage this wave's 6 weight rows into LDS (float4 loads) ----
        const int ustride = 3 * Din + 3 * H_DIM;
        float* L = lds + wv * ustride;
        for (int g = 0; g < 3; ++g) {
            const float4* src = (const float4*)(wih + (size_t)(j + g * H_DIM) * Din);
            float4* dst = (float4*)(L + g * Din);
            for (int k = lane; k < Din / 4; k += 64) dst[k] = src[k];
        }
        for (int g = 0; g < 3; ++g) {
            const float4* src = (const float4*)(whh + (size_t)(j + g * H_DIM) * H_DIM);
            float4* dst = (float4*)(L + 3 * Din + g * H_DIM);
            for (int k = lane; k < H_DIM / 4; k += 64) dst[k] = src[k];
        }
        const float bir = bih[j], biz = bih[j + 768], bin_ = bih[j + 1536];
        const float bhr = bhh[j], bhz = bhh[j + 768], bhn  = bhh[j + 1536];
        __syncthreads();

        const float* Lihr = L;
        const float* Lihz = L + Din;
        const float* Lihn = L + 2 * Din;
        const float* Lhr  = L + 3 * Din;
        const float* Lhz  = Lhr + H_DIM;
        const float* Lhn  = Lhz + H_DIM;

        // ---- gi partials for t=0 (prefetched thereafter) ----
        float pir = 0.f, piz = 0.f, pin_ = 0.f;
        {
            if (l == 0) {
                const float* xr = x;
#pragma unroll
                for (int kk = 0; kk < IN0 / 64; ++kk) {
                    const int k = lane + kk * 64;
                    const float xv = xr[k];
                    pir += xv * Lihr[k]; piz += xv * Lihz[k]; pin_ += xv * Lihn[k];
                }
            } else {
                const float* xr = yp;
#pragma unroll
                for (int kk = 0; kk < H_DIM / 64; ++kk) {
                    const int k = lane + kk * 64;
                    const float xv = xr[k];
                    pir += xv * Lihr[k]; piz += xv * Lihz[k]; pin_ += xv * Lihn[k];
                }
            }
        }

        for (int t = 0; t < T_SEQ; ++t) {
            float air = pir, aiz = piz, ain = pin_;
            float ahr = 0.f, ahz = 0.f, ahn = 0.f;

            // hidden projection (h_{t-1} visible after previous barrier)
            float hprev = 0.f;
            if (t > 0) {
                const float* hr = yc + (size_t)(t - 1) * H_DIM;
                hprev = hr[j];
#pragma unroll
                for (int kk = 0; kk < H_DIM / 64; ++kk) {
                    const int k = lane + kk * 64;
                    const float hv = hr[k];
                    ahr += hv * Lhr[k]; ahz += hv * Lhz[k]; ahn += hv * Lhn[k];
                }
            }

            // 64-lane butterfly reduce, 6 accumulators
#pragma unroll
            for (int off = 32; off > 0; off >>= 1) {
                air += __shfl_xor(air, off, 64);
                aiz += __shfl_xor(aiz, off, 64);
                ain += __shfl_xor(ain, off, 64);
                ahr += __shfl_xor(ahr, off, 64);
                ahz += __shfl_xor(ahz, off, 64);
                ahn += __shfl_xor(ahn, off, 64);
            }

            if (lane == 0) {
                const float r = sigm(air + bir + ahr + bhr);
                const float z = sigm(aiz + biz + ahz + bhz);
                const float n = tanhf(ain + bin_ + r * (ahn + bhn));
                yc[(size_t)t * H_DIM + j] = (1.f - z) * n + z * hprev;
            }

            // ---- arrive ----
            __threadfence();
            __syncthreads();
            ++gstep;
            if (tid == 0)
                __hip_atomic_store(&slots[bid * SLOT_STRIDE], gstep,
                                   __ATOMIC_RELEASE, __HIP_MEMORY_SCOPE_AGENT);

            // ---- gi prefetch for t+1 (independent of h_t; hides in wait) ----
            pir = 0.f; piz = 0.f; pin_ = 0.f;
            if (t + 1 < T_SEQ) {
                if (l == 0) {
                    const float* xr = x + (size_t)(t + 1) * IN0;
#pragma unroll
                    for (int kk = 0; kk < IN0 / 64; ++kk) {
                        const int k = lane + kk * 64;
                        const float xv = xr[k];
                        pir += xv * Lihr[k]; piz += xv * Lihz[k]; pin_ += xv * Lihn[k];
                    }
                } else {
                    const float* xr = yp + (size_t)(t + 1) * H_DIM;
#pragma unroll
                    for (int kk = 0; kk < H_DIM / 64; ++kk) {
                        const int k = lane + kk * 64;
                        const float xv = xr[k];
                        pir += xv * Lihr[k]; piz += xv * Lihz[k]; pin_ += xv * Lihn[k];
                    }
                }
            }

            // ---- wait for release ----
            if (tid == 0) {
                while (__hip_atomic_load(flag, __ATOMIC_ACQUIRE,
                                         __HIP_MEMORY_SCOPE_AGENT) < gstep)
                    __builtin_amdgcn_s_sleep(2);
            }
            __syncthreads();
        }
    }
}

extern "C" __global__ __launch_bounds__(NOUT, 1) void fc_head(
    const float* __restrict__ h,
    const float* __restrict__ fw,
    const float* __restrict__ fb,
    float* __restrict__ out)
{
    __shared__ float hs[H_DIM];
    const int t = blockIdx.x;
    const float* hr = h + (size_t)t * H_DIM;
    for (int k = threadIdx.x; k < H_DIM; k += NOUT) hs[k] = hr[k];
    __syncthreads();

    const int o = threadIdx.x;
    float acc = fb[o];
    const float* wr = fw + (size_t)o * H_DIM;
#pragma unroll 8
    for (int k = 0; k < H_DIM; ++k) acc += hs[k] * wr[k];
    out[(size_t)t * NOUT + o] = acc;
}

extern "C" void kernel_launch(void* const* d_in, const int* in_sizes, int n_in,
                              void* d_out, int out_size, void* d_ws, size_t ws_size,
                              hipStream_t stream)
{
    const float* x    = (const float*)d_in[0];
    const float* wih0 = (const float*)d_in[1];
    const float* whh0 = (const float*)d_in[2];
    const float* bih0 = (const float*)d_in[3];
    const float* bhh0 = (const float*)d_in[4];
    const float* wihS = (const float*)d_in[5];
    const float* whhS = (const float*)d_in[6];
    const float* bihS = (const float*)d_in[7];
    const float* bhhS = (const float*)d_in[8];
    const float* fcw  = (const float*)d_in[9];
    const float* fcb  = (const float*)d_in[10];

    char* ws = (char*)d_ws;
    unsigned int* ctr = (unsigned int*)ws;          // flag + slot array
    float* buf0 = (float*)(ws + 65536);             // [2048,768] fp32
    float* buf1 = buf0 + (size_t)T_SEQ * H_DIM;     // [2048,768] fp32

    hipMemsetAsync(ctr, 0, 65536, stream);          // zero flag + slots

    hipLaunchKernelGGL(gru_persistent, dim3(NBLK + 1), dim3(NTHR), 0, stream,
                       x, wih0, whh0, bih0, bhh0, wihS, whhS, bihS, bhhS,
                       buf0, buf1, ctr);

    // layer 9 (odd) wrote buf1
    hipLaunchKernelGGL(fc_head, dim3(T_SEQ), dim3(NOUT), 0, stream,
                       buf1, fcw, fcb, (float*)d_out);
}

// Round 4
// 37415.594 us; speedup vs baseline: 15.4167x; 15.4167x over previous
//
#include <hip/hip_runtime.h>
#include <hip/hip_bf16.h>

// TrainerRNN: 10-layer GRU (T=2048, IN=384, H=768) + linear head (384).
// ROUND 3: fence-free device coherence.
// R1 (24.4 us/step) and R2 (28.2 us/step, checker regression) were dominated
// NOT by arrival contention but by fence-emitted cache ops: __threadfence
// (agent release) -> buffer_wbl2 (full L2 writeback); ACQUIRE polls ->
// buffer_inv (L2 invalidate). 32 blocks/XCD x per-step whole-L2 ops ~ 25 us,
// and the invalidates forced weight/activation refetch (FETCH_SIZE 911 MB).
// Fix: ALL cross-block data (h, prev-layer activations) moves via RELAXED
// AGENT atomics (global_load/store sc1 -> LLC point-of-coherence; L2 never
// holds these lines -> nothing can go stale -> NO fences, NO cache ops).
// Ordering: producer h-store acked by the s_waitcnt vmcnt(0) inside
// __syncthreads before arrival; consumer ordering by program order + barrier.
// Barrier: 64 padded group counters (4 blocks each, relaxed fetch_add);
// wave 0 of every block scans them (1 load/lane, __all). No checker block.

#define T_SEQ 2048
#define H_DIM 768
#define IN0   384
#define G3    2304      // 3*H
#define NLAYER 10
#define NBLK  256
#define NTHR  192       // 3 waves, one per owned hidden unit
#define NOUT  384
#define NCTR  64        // barrier group counters (4 blocks each)
#define CTR_STRIDE 32   // 128 B apart

__device__ __forceinline__ float sigm(float x) { return 1.0f / (1.0f + __expf(-x)); }

__device__ __forceinline__ float ldg_dev(const float* p) {
    return __hip_atomic_load(p, __ATOMIC_RELAXED, __HIP_MEMORY_SCOPE_AGENT);
}
__device__ __forceinline__ void stg_dev(float* p, float v) {
    __hip_atomic_store(p, v, __ATOMIC_RELAXED, __HIP_MEMORY_SCOPE_AGENT);
}

extern "C" __global__ __launch_bounds__(NTHR, 1) void gru_persistent(
    const float* __restrict__ x,
    const float* __restrict__ wih0,
    const float* __restrict__ whh0,
    const float* __restrict__ bih0,
    const float* __restrict__ bhh0,
    const float* __restrict__ wihS,
    const float* __restrict__ whhS,
    const float* __restrict__ bihS,
    const float* __restrict__ bhhS,
    float* __restrict__ buf0, float* __restrict__ buf1,
    unsigned int* __restrict__ ctr)
{
    __shared__ float lds[3 * 6 * H_DIM];   // 3 units * 4608 floats = 54 KB

    const int tid  = threadIdx.x;
    const int lane = tid & 63;
    const int wv   = tid >> 6;             // 0..2
    const int bid  = blockIdx.x;
    const int j    = bid * 3 + wv;         // owned hidden unit, 0..767
    unsigned int gstep = 0;

    for (int l = 0; l < NLAYER; ++l) {
        const int Din = (l == 0) ? IN0 : H_DIM;
        const float* wih = (l == 0) ? wih0 : wihS + (size_t)(l - 1) * G3 * H_DIM;
        const float* whh = (l == 0) ? whh0 : whhS + (size_t)(l - 1) * G3 * H_DIM;
        const float* bih = (l == 0) ? bih0 : bihS + (size_t)(l - 1) * G3;
        const float* bhh = (l == 0) ? bhh0 : bhhS + (size_t)(l - 1) * G3;
        const float* yp = (l & 1) ? buf0 : buf1;   // prev layer output (l>0)
        float*       yc = (l & 1) ? buf1 : buf0;   // this layer's output

        // ---- stage this wave's 6 weight rows into LDS (plain float4) ----
        const int ustride = 3 * Din + 3 * H_DIM;
        float* L = lds + wv * ustride;
        for (int g = 0; g < 3; ++g) {
            const float4* src = (const float4*)(wih + (size_t)(j + g * H_DIM) * Din);
            float4* dst = (float4*)(L + g * Din);
            for (int k = lane; k < Din / 4; k += 64) dst[k] = src[k];
        }
        for (int g = 0; g < 3; ++g) {
            const float4* src = (const float4*)(whh + (size_t)(j + g * H_DIM) * H_DIM);
            float4* dst = (float4*)(L + 3 * Din + g * H_DIM);
            for (int k = lane; k < H_DIM / 4; k += 64) dst[k] = src[k];
        }
        const float bir = bih[j], biz = bih[j + 768], bin_ = bih[j + 1536];
        const float bhr = bhh[j], bhz = bhh[j + 768], bhn  = bhh[j + 1536];
        __syncthreads();

        const float* Lihr = L;
        const float* Lihz = L + Din;
        const float* Lihn = L + 2 * Din;
        const float* Lhr  = L + 3 * Din;
        const float* Lhz  = Lhr + H_DIM;
        const float* Lhn  = Lhz + H_DIM;

        // ---- gi partials for t=0 (prefetched thereafter) ----
        float pir = 0.f, piz = 0.f, pin_ = 0.f;
        if (l == 0) {
#pragma unroll
            for (int kk = 0; kk < IN0 / 64; ++kk) {
                const int k = lane + kk * 64;
                const float xv = x[k];
                pir += xv * Lihr[k]; piz += xv * Lihz[k]; pin_ += xv * Lihn[k];
            }
        } else {
#pragma unroll
            for (int kk = 0; kk < H_DIM / 64; ++kk) {
                const int k = lane + kk * 64;
                const float xv = ldg_dev(yp + k);
                pir += xv * Lihr[k]; piz += xv * Lihz[k]; pin_ += xv * Lihn[k];
            }
        }

        for (int t = 0; t < T_SEQ; ++t) {
            float ahr = 0.f, ahz = 0.f, ahn = 0.f;
            float hprev = 0.f;

            // hidden projection (h_{t-1} coherent at LLC after prev barrier)
            if (t > 0) {
                const float* hr = yc + (size_t)(t - 1) * H_DIM;
                hprev = ldg_dev(hr + j);          // wave-uniform address
#pragma unroll
                for (int kk = 0; kk < H_DIM / 64; ++kk) {
                    const int k = lane + kk * 64;
                    const float hv = ldg_dev(hr + k);
                    ahr += hv * Lhr[k]; ahz += hv * Lhz[k]; ahn += hv * Lhn[k];
                }
            }

            // combine input+hidden partials for r,z; reduce 4 values
            float sr = pir + ahr, sz = piz + ahz, sni = pin_, snh = ahn;
#pragma unroll
            for (int off = 32; off > 0; off >>= 1) {
                sr  += __shfl_xor(sr,  off, 64);
                sz  += __shfl_xor(sz,  off, 64);
                sni += __shfl_xor(sni, off, 64);
                snh += __shfl_xor(snh, off, 64);
            }

            if (lane == 0) {
                const float r = sigm(sr + bir + bhr);
                const float z = sigm(sz + biz + bhz);
                const float n = tanhf(sni + bin_ + r * (snh + bhn));
                stg_dev(&yc[(size_t)t * H_DIM + j], (1.f - z) * n + z * hprev);
            }

            // ---- arrive: syncthreads drains the sc1 h-store (vmcnt(0)),
            //      then one relaxed RMW into this block's group counter ----
            __syncthreads();
            ++gstep;
            if (tid == 0)
                __hip_atomic_fetch_add(&ctr[(bid >> 2) * CTR_STRIDE], 1u,
                                       __ATOMIC_RELAXED, __HIP_MEMORY_SCOPE_AGENT);

            // ---- gi prefetch for t+1 (independent of h_t; hides in wait) ----
            pir = 0.f; piz = 0.f; pin_ = 0.f;
            if (t + 1 < T_SEQ) {
                if (l == 0) {
                    const float* xr = x + (size_t)(t + 1) * IN0;
#pragma unroll
                    for (int kk = 0; kk < IN0 / 64; ++kk) {
                        const int k = lane + kk * 64;
                        const float xv = xr[k];
                        pir += xv * Lihr[k]; piz += xv * Lihz[k]; pin_ += xv * Lihn[k];
                    }
                } else {
                    const float* xr = yp + (size_t)(t + 1) * H_DIM;
#pragma unroll
                    for (int kk = 0; kk < H_DIM / 64; ++kk) {
                        const int k = lane + kk * 64;
                        const float xv = ldg_dev(xr + k);
                        pir += xv * Lihr[k]; piz += xv * Lihz[k]; pin_ += xv * Lihn[k];
                    }
                }
            }

            // ---- wait: wave 0 scans the 64 group counters (1 per lane) ----
            if (wv == 0) {
                const unsigned int tgt = 4u * gstep;
                for (;;) {
                    const unsigned int v = __hip_atomic_load(
                        &ctr[lane * CTR_STRIDE],
                        __ATOMIC_RELAXED, __HIP_MEMORY_SCOPE_AGENT);
                    if (__all(v >= tgt)) break;
                    __builtin_amdgcn_s_sleep(4);
                }
            }
            __syncthreads();
        }
    }
}

extern "C" __global__ __launch_bounds__(NOUT, 1) void fc_head(
    const float* __restrict__ h,
    const float* __restrict__ fw,
    const float* __restrict__ fb,
    float* __restrict__ out)
{
    __shared__ float hs[H_DIM];
    const int t = blockIdx.x;
    const float* hr = h + (size_t)t * H_DIM;
    for (int k = threadIdx.x; k < H_DIM; k += NOUT) hs[k] = hr[k];
    __syncthreads();

    const int o = threadIdx.x;
    float acc = fb[o];
    const float* wr = fw + (size_t)o * H_DIM;
#pragma unroll 8
    for (int k = 0; k < H_DIM; ++k) acc += hs[k] * wr[k];
    out[(size_t)t * NOUT + o] = acc;
}

extern "C" void kernel_launch(void* const* d_in, const int* in_sizes, int n_in,
                              void* d_out, int out_size, void* d_ws, size_t ws_size,
                              hipStream_t stream)
{
    const float* x    = (const float*)d_in[0];
    const float* wih0 = (const float*)d_in[1];
    const float* whh0 = (const float*)d_in[2];
    const float* bih0 = (const float*)d_in[3];
    const float* bhh0 = (const float*)d_in[4];
    const float* wihS = (const float*)d_in[5];
    const float* whhS = (const float*)d_in[6];
    const float* bihS = (const float*)d_in[7];
    const float* bhhS = (const float*)d_in[8];
    const float* fcw  = (const float*)d_in[9];
    const float* fcb  = (const float*)d_in[10];

    char* ws = (char*)d_ws;
    unsigned int* ctr = (unsigned int*)ws;          // 64 group counters, padded
    float* buf0 = (float*)(ws + 65536);             // [2048,768] fp32
    float* buf1 = buf0 + (size_t)T_SEQ * H_DIM;     // [2048,768] fp32

    hipMemsetAsync(ctr, 0, 65536, stream);          // zero counters

    hipLaunchKernelGGL(gru_persistent, dim3(NBLK), dim3(NTHR), 0, stream,
                       x, wih0, whh0, bih0, bhh0, wihS, whhS, bihS, bhhS,
                       buf0, buf1, ctr);

    // layer 9 (odd) wrote buf1
    hipLaunchKernelGGL(fc_head, dim3(T_SEQ), dim3(NOUT), 0, stream,
                       buf1, fcw, fcb, (float*)d_out);
}